// Round 2
// baseline (9821.973 us; speedup 1.0000x reference)
//
#include <hip/hip_runtime.h>

// Sinkhorn-log barycentric mapping, N=M=8192, D=128, reg=0.05, 50 iters.
// d_out layout: [ mapped: N*D f32 | pi: N*M f32 ].
// Mr = -C/reg is materialized in the pi region (overwritten by pi at the end).
// Fast path (ws_size >= 128 KB): u,v,xx,yy in d_ws; part,cnt in the mapped
// region (dead before the final fused pi+mapped kernel writes mapped).
// Slow path: old layout, separate k_pi + k_mapped.

#define NN 8192
#define MMX 8192
#define DD 128
#define NITER 50
#define LOGAB (-9.0109133472792881f)   /* log(1/8192) = -13*ln2 */
#define NEG20 (-20.0f)                 /* -1/reg */

static __device__ __forceinline__ void lse_acc(float& m, float& s, float x) {
    float mn = fmaxf(m, x);
    s = s * __expf(m - mn) + __expf(x - mn);
    m = mn;
}
static __device__ __forceinline__ void lse_merge(float& m, float& s, float m2, float s2) {
    float mn = fmaxf(m, m2);
    s = s * __expf(m - mn) + s2 * __expf(m2 - mn);
    m = mn;
}
static __device__ __forceinline__ void lse_acc4(float4& m, float4& s, float4 x) {
    lse_acc(m.x, s.x, x.x);
    lse_acc(m.y, s.y, x.y);
    lse_acc(m.z, s.z, x.z);
    lse_acc(m.w, s.w, x.w);
}
static __device__ __forceinline__ int swz(int r, int k) {
    return k ^ (((r >> 3) & 7) << 2);
}

// ---- zero u, v, cnt ---------------------------------------------------------
__global__ void k_init(float* u, float* v, int* cnt) {
    int i = blockIdx.x * 1024 + threadIdx.x;
    if (i < 8192) { u[i] = 0.0f; v[i] = 0.0f; }
    if (blockIdx.x == 0 && threadIdx.x < 8) cnt[threadIdx.x] = 0;
}

// ---- squared norms: one wave per row ---------------------------------------
__global__ __launch_bounds__(64) void k_sqnorm(const float* __restrict__ XP,
                                               const float* __restrict__ XQ,
                                               float* __restrict__ xx,
                                               float* __restrict__ yy) {
    int row = blockIdx.x;
    int lane = threadIdx.x;
    const float* src = (row < NN) ? (XP + (size_t)row * DD)
                                  : (XQ + (size_t)(row - NN) * DD);
    float2 w = *(const float2*)&src[lane * 2];
    float sres = w.x * w.x + w.y * w.y;
    #pragma unroll
    for (int off = 32; off > 0; off >>= 1)
        sres += __shfl_down(sres, off, 64);
    if (lane == 0) {
        if (row < NN) xx[row] = sres;
        else          yy[row - NN] = sres;
    }
}

// ---- Mr = -20 * max(0, xx + yy - 2 XP.XQ^T) --------------------------------
__global__ __launch_bounds__(256, 1) void k_gemm_mr(const float* __restrict__ XP,
                                                    const float* __restrict__ XQ,
                                                    const float* __restrict__ xx,
                                                    const float* __restrict__ yy,
                                                    float* __restrict__ Mr) {
    __shared__ float As[128][128];
    __shared__ float Bs[128][128];
    int rb = blockIdx.y * 128, cb = blockIdx.x * 128;
    int t = threadIdx.x;

    #pragma unroll
    for (int i = 0; i < 16; ++i) {
        int f = i * 256 + t;
        int r = f >> 5;
        int k4 = (f & 31) * 4;
        *(float4*)&As[r][swz(r, k4)] = *(const float4*)&XP[(size_t)(rb + r) * DD + k4];
        *(float4*)&Bs[r][swz(r, k4)] = *(const float4*)&XQ[(size_t)(cb + r) * DD + k4];
    }
    __syncthreads();

    int ty = t >> 4, tx = t & 15;
    int r0 = ty * 8, c0 = tx * 8;
    float acc[8][8] = {};

    for (int k = 0; k < 128; k += 4) {
        float4 a[8], b[8];
        #pragma unroll
        for (int i = 0; i < 8; ++i) {
            a[i] = *(float4*)&As[r0 + i][swz(r0 + i, k)];
            b[i] = *(float4*)&Bs[c0 + i][swz(c0 + i, k)];
        }
        #pragma unroll
        for (int i = 0; i < 8; ++i)
            #pragma unroll
            for (int j = 0; j < 8; ++j)
                acc[i][j] += a[i].x * b[j].x + a[i].y * b[j].y +
                             a[i].z * b[j].z + a[i].w * b[j].w;
    }

    float yv[8];
    *(float4*)&yv[0] = *(const float4*)&yy[cb + c0];
    *(float4*)&yv[4] = *(const float4*)&yy[cb + c0 + 4];
    #pragma unroll
    for (int i = 0; i < 8; ++i) {
        int gr = rb + r0 + i;
        float xxi = xx[gr];
        float4 o0, o1;
        o0.x = NEG20 * fmaxf(xxi + yv[0] - 2.f * acc[i][0], 0.f);
        o0.y = NEG20 * fmaxf(xxi + yv[1] - 2.f * acc[i][1], 0.f);
        o0.z = NEG20 * fmaxf(xxi + yv[2] - 2.f * acc[i][2], 0.f);
        o0.w = NEG20 * fmaxf(xxi + yv[3] - 2.f * acc[i][3], 0.f);
        o1.x = NEG20 * fmaxf(xxi + yv[4] - 2.f * acc[i][4], 0.f);
        o1.y = NEG20 * fmaxf(xxi + yv[5] - 2.f * acc[i][5], 0.f);
        o1.z = NEG20 * fmaxf(xxi + yv[6] - 2.f * acc[i][6], 0.f);
        o1.w = NEG20 * fmaxf(xxi + yv[7] - 2.f * acc[i][7], 0.f);
        *(float4*)&Mr[(size_t)gr * MMX + cb + c0] = o0;
        *(float4*)&Mr[(size_t)gr * MMX + cb + c0 + 4] = o1;
    }
}

// ---- column-LSE partial + fused last-block combine --------------------------
__global__ __launch_bounds__(256) void k_colpass(const float* __restrict__ Mr,
                                                 const float* __restrict__ u,
                                                 float* __restrict__ part,
                                                 int* __restrict__ cnt,
                                                 float* __restrict__ v) {
    int c = blockIdx.x * 1024 + threadIdx.x * 4;
    int n0 = blockIdx.y * 128;
    float4 mx = make_float4(-1e30f, -1e30f, -1e30f, -1e30f);
    float4 s = make_float4(0.f, 0.f, 0.f, 0.f);
    #pragma unroll 4
    for (int r = 0; r < 128; ++r) {
        float un = u[n0 + r];
        float4 w = *(const float4*)&Mr[(size_t)(n0 + r) * MMX + c];
        w.x += un; w.y += un; w.z += un; w.w += un;
        lse_acc4(mx, s, w);
    }
    float4 o;
    o.x = mx.x + __logf(s.x);
    o.y = mx.y + __logf(s.y);
    o.z = mx.z + __logf(s.z);
    o.w = mx.w + __logf(s.w);
    *(float4*)&part[(size_t)blockIdx.y * MMX + c] = o;

    // last block of this column-group combines the 64 chunk partials -> v
    __shared__ int lastflag;
    __threadfence();
    if (threadIdx.x == 0) lastflag = atomicAdd(&cnt[blockIdx.x], 1);
    __syncthreads();
    if (lastflag != 63) return;
    __threadfence();
    int cb = blockIdx.x * 1024;
    for (int cc = threadIdx.x; cc < 1024; cc += 256) {
        float m1 = -1e30f, s1 = 0.f;
        #pragma unroll 8
        for (int ch = 0; ch < 64; ++ch)
            lse_acc(m1, s1, part[(size_t)ch * MMX + cb + cc]);
        v[cb + cc] = LOGAB - (m1 + __logf(s1));
    }
    if (threadIdx.x == 0) atomicExch(&cnt[blockIdx.x], 0);   // replay-safe reset
}

// ---- row-LSE: block = 8 rows (v reload amortized 8x) ------------------------
__global__ __launch_bounds__(256) void k_rowpass(const float* __restrict__ Mr,
                                                 const float* __restrict__ v,
                                                 float* __restrict__ u) {
    int n0 = blockIdx.x * 8;
    int t = threadIdx.x;
    float4 mx[8], s[8];
    #pragma unroll
    for (int r = 0; r < 8; ++r) {
        mx[r] = make_float4(-1e30f, -1e30f, -1e30f, -1e30f);
        s[r] = make_float4(0.f, 0.f, 0.f, 0.f);
    }
    const float4* v4 = (const float4*)v;
    for (int i = t; i < MMX / 4; i += 256) {
        float4 vv = v4[i];
        #pragma unroll
        for (int r = 0; r < 8; ++r) {
            float4 w = *(const float4*)&Mr[(size_t)(n0 + r) * MMX + i * 4];
            w.x += vv.x; w.y += vv.y; w.z += vv.z; w.w += vv.w;
            lse_acc4(mx[r], s[r], w);
        }
    }
    __shared__ float smm[8][4], sss[8][4];
    int wid = t >> 6, lane = t & 63;
    #pragma unroll
    for (int r = 0; r < 8; ++r) {
        float m1 = mx[r].x, s1 = s[r].x;
        lse_merge(m1, s1, mx[r].y, s[r].y);
        lse_merge(m1, s1, mx[r].z, s[r].z);
        lse_merge(m1, s1, mx[r].w, s[r].w);
        #pragma unroll
        for (int off = 32; off > 0; off >>= 1) {
            float m2 = __shfl_xor(m1, off);
            float s2 = __shfl_xor(s1, off);
            lse_merge(m1, s1, m2, s2);
        }
        if (lane == 0) { smm[r][wid] = m1; sss[r][wid] = s1; }
    }
    __syncthreads();
    if (t < 8) {
        float m1 = smm[t][0], s1 = sss[t][0];
        lse_merge(m1, s1, smm[t][1], sss[t][1]);
        lse_merge(m1, s1, smm[t][2], sss[t][2]);
        lse_merge(m1, s1, smm[t][3], sss[t][3]);
        u[n0 + t] = LOGAB - (m1 + __logf(s1));
    }
}

// ---- FUSED: pi = exp(Mr+u+v) (in place) AND mapped = 8192 * pi @ XQ ---------
// grid 256 (32-row strips), 512 threads. Thread-tile 4r x 4d, 2-way k-split.
// u,v must NOT live in the mapped region (they're read throughout).
__global__ __launch_bounds__(512, 1) void k_pi_mapped(float* __restrict__ P,
                                                      const float* __restrict__ XQ,
                                                      const float* __restrict__ u,
                                                      const float* __restrict__ v,
                                                      float* __restrict__ mapped) {
    __shared__ float PIs[32][68];      // +4 pad: spread row-strided b128 writes
    __shared__ float QS[64][128];      // also reused for the acc merge (16 KB)
    int r0 = blockIdx.x * 32;
    int t = threadIdx.x;               // 0..511
    int tid = t & 255;
    int half = t >> 8;
    int rg = tid >> 5;                 // 0..7  -> rows rg*4..rg*4+3
    int dg = tid & 31;                 // 0..31 -> dims dg*4..dg*4+3
    int prow = t >> 4;                 // pi-stage row (0..31)
    int pc4 = (t & 15) * 4;            // pi-stage col
    int qrb = t >> 5;                  // XQ-stage row base
    int qc4 = (t & 31) * 4;            // XQ-stage col
    float urow = u[r0 + prow];

    float4 acc[4];
    acc[0] = acc[1] = acc[2] = acc[3] = make_float4(0.f, 0.f, 0.f, 0.f);

    // prefetch chunk 0
    float4 pw, vv, xq0, xq1, xq2, xq3;
    pw = *(const float4*)&P[(size_t)(r0 + prow) * MMX + pc4];
    vv = *(const float4*)&v[pc4];
    xq0 = *(const float4*)&XQ[(size_t)(qrb) * DD + qc4];
    xq1 = *(const float4*)&XQ[(size_t)(16 + qrb) * DD + qc4];
    xq2 = *(const float4*)&XQ[(size_t)(32 + qrb) * DD + qc4];
    xq3 = *(const float4*)&XQ[(size_t)(48 + qrb) * DD + qc4];

    for (int mb = 0; mb < MMX; mb += 64) {
        __syncthreads();               // (a) prior compute done; prefetch drained
        // stage to LDS (exp in register)
        float4 w;
        w.x = __expf(pw.x + urow + vv.x);
        w.y = __expf(pw.y + urow + vv.y);
        w.z = __expf(pw.z + urow + vv.z);
        w.w = __expf(pw.w + urow + vv.w);
        *(float4*)&PIs[prow][pc4] = w;
        *(float4*)&QS[qrb][qc4] = xq0;
        *(float4*)&QS[16 + qrb][qc4] = xq1;
        *(float4*)&QS[32 + qrb][qc4] = xq2;
        *(float4*)&QS[48 + qrb][qc4] = xq3;
        __syncthreads();               // (b) LDS ready
        // global pi write + prefetch next chunk (latency hidden under compute)
        *(float4*)&P[(size_t)(r0 + prow) * MMX + mb + pc4] = w;
        if (mb + 64 < MMX) {
            int nb = mb + 64;
            pw = *(const float4*)&P[(size_t)(r0 + prow) * MMX + nb + pc4];
            vv = *(const float4*)&v[nb + pc4];
            xq0 = *(const float4*)&XQ[(size_t)(nb + qrb) * DD + qc4];
            xq1 = *(const float4*)&XQ[(size_t)(nb + 16 + qrb) * DD + qc4];
            xq2 = *(const float4*)&XQ[(size_t)(nb + 32 + qrb) * DD + qc4];
            xq3 = *(const float4*)&XQ[(size_t)(nb + 48 + qrb) * DD + qc4];
        }
        // GEMM: halves split the 16 k-steps of this 64-m chunk
        #pragma unroll
        for (int sstep = 0; sstep < 8; ++sstep) {
            int k = (half * 8 + sstep) * 4;
            float4 q0 = *(float4*)&QS[k + 0][dg * 4];
            float4 q1 = *(float4*)&QS[k + 1][dg * 4];
            float4 q2 = *(float4*)&QS[k + 2][dg * 4];
            float4 q3 = *(float4*)&QS[k + 3][dg * 4];
            #pragma unroll
            for (int j = 0; j < 4; ++j) {
                float4 p = *(float4*)&PIs[rg * 4 + j][k];
                acc[j].x += p.x * q0.x + p.y * q1.x + p.z * q2.x + p.w * q3.x;
                acc[j].y += p.x * q0.y + p.y * q1.y + p.z * q2.y + p.w * q3.y;
                acc[j].z += p.x * q0.z + p.y * q1.z + p.z * q2.z + p.w * q3.z;
                acc[j].w += p.x * q0.w + p.y * q1.w + p.z * q2.w + p.w * q3.w;
            }
        }
    }
    // merge halves through LDS (reuse QS) and write mapped
    __syncthreads();
    float* mrg = &QS[0][0];
    if (half == 1) {
        #pragma unroll
        for (int j = 0; j < 4; ++j)
            *(float4*)&mrg[tid * 16 + j * 4] = acc[j];
    }
    __syncthreads();
    if (half == 0) {
        #pragma unroll
        for (int j = 0; j < 4; ++j) {
            float4 o = *(const float4*)&mrg[tid * 16 + j * 4];
            o.x = (acc[j].x + o.x) * 8192.f;
            o.y = (acc[j].y + o.y) * 8192.f;
            o.z = (acc[j].z + o.z) * 8192.f;
            o.w = (acc[j].w + o.w) * 8192.f;
            *(float4*)&mapped[(size_t)(r0 + rg * 4 + j) * DD + dg * 4] = o;
        }
    }
}

// ---- fallback path (ws too small): old separate pi / mapped -----------------
__global__ __launch_bounds__(256) void k_pi(float* __restrict__ Mr,
                                            const float* __restrict__ u,
                                            const float* __restrict__ v) {
    const float4* v4 = (const float4*)v;
    for (int i = blockIdx.x * 256 + threadIdx.x; i < NN * MMX / 4; i += 2048 * 256) {
        int n = i >> 11;
        int m4 = i & 2047;
        float un = u[n];
        float4 vv = v4[m4];
        float4* p = (float4*)Mr + i;
        float4 w = *p;
        w.x = __expf(w.x + un + vv.x);
        w.y = __expf(w.y + un + vv.y);
        w.z = __expf(w.z + un + vv.z);
        w.w = __expf(w.w + un + vv.w);
        *p = w;
    }
}

__global__ __launch_bounds__(256) void k_mapped(const float* __restrict__ pi,
                                                const float* __restrict__ XQ,
                                                float* __restrict__ mapped) {
    __shared__ float XQs[64][128];
    __shared__ float PIs[32][64];
    int r0 = blockIdx.x * 32;
    int t = threadIdx.x;
    int dg = (t & 31) * 4;
    int rg = (t >> 5) * 4;
    float4 acc[4];
    #pragma unroll
    for (int j = 0; j < 4; ++j) acc[j] = make_float4(0.f, 0.f, 0.f, 0.f);

    for (int mb = 0; mb < MMX; mb += 64) {
        __syncthreads();
        #pragma unroll
        for (int i = 0; i < 8; ++i) {
            int f = i * 256 + t;
            int rr = f >> 5;
            int k4 = (f & 31) * 4;
            *(float4*)&XQs[rr][k4] = *(const float4*)&XQ[(size_t)(mb + rr) * DD + k4];
        }
        #pragma unroll
        for (int i = 0; i < 2; ++i) {
            int f = i * 256 + t;
            int rr = f >> 4;
            int c4 = (f & 15) * 4;
            *(float4*)&PIs[rr][c4] = *(const float4*)&pi[(size_t)(r0 + rr) * MMX + mb + c4];
        }
        __syncthreads();
        for (int mm = 0; mm < 64; mm += 4) {
            float4 q0 = *(float4*)&XQs[mm + 0][dg];
            float4 q1 = *(float4*)&XQs[mm + 1][dg];
            float4 q2 = *(float4*)&XQs[mm + 2][dg];
            float4 q3 = *(float4*)&XQs[mm + 3][dg];
            #pragma unroll
            for (int j = 0; j < 4; ++j) {
                float4 p = *(float4*)&PIs[rg + j][mm];
                acc[j].x += p.x * q0.x + p.y * q1.x + p.z * q2.x + p.w * q3.x;
                acc[j].y += p.x * q0.y + p.y * q1.y + p.z * q2.y + p.w * q3.y;
                acc[j].z += p.x * q0.z + p.y * q1.z + p.z * q2.z + p.w * q3.z;
                acc[j].w += p.x * q0.w + p.y * q1.w + p.z * q2.w + p.w * q3.w;
            }
        }
    }
    #pragma unroll
    for (int j = 0; j < 4; ++j) {
        float4 o = acc[j];
        o.x *= 8192.f; o.y *= 8192.f; o.z *= 8192.f; o.w *= 8192.f;
        *(float4*)&mapped[(size_t)(r0 + rg + j) * DD + dg] = o;
    }
}

extern "C" void kernel_launch(void* const* d_in, const int* in_sizes, int n_in,
                              void* d_out, int out_size, void* d_ws, size_t ws_size,
                              hipStream_t stream) {
    const float* XP = (const float*)d_in[0];
    const float* XQ = (const float*)d_in[1];
    float* out = (float*)d_out;
    float* Mr = out + (size_t)NN * DD;            // pi region: Mr then pi
    float* part = out + 65536;                    // 64 x 8192 partials (2 MiB)
    int* cnt = (int*)(out + 65536 + 64 * 8192);   // 8 combine counters

    bool fast = (ws_size >= 131072);
    float* u  = fast ? (float*)d_ws           : out;
    float* v  = fast ? (float*)d_ws + 8192    : out + 8192;
    float* xx = fast ? (float*)d_ws + 16384   : out + 40960;
    float* yy = fast ? (float*)d_ws + 24576   : out + 49152;

    k_init<<<8, 1024, 0, stream>>>(u, v, cnt);
    k_sqnorm<<<NN + MMX, 64, 0, stream>>>(XP, XQ, xx, yy);
    k_gemm_mr<<<dim3(64, 64), 256, 0, stream>>>(XP, XQ, xx, yy, Mr);

    for (int it = 0; it < NITER; ++it) {
        k_colpass<<<dim3(8, 64), 256, 0, stream>>>(Mr, u, part, cnt, v);
        k_rowpass<<<1024, 256, 0, stream>>>(Mr, v, u);
    }

    if (fast) {
        k_pi_mapped<<<256, 512, 0, stream>>>(Mr, XQ, u, v, out);
    } else {
        k_pi<<<2048, 256, 0, stream>>>(Mr, u, v);
        k_mapped<<<256, 256, 0, stream>>>(Mr, XQ, out);
    }
}

// Round 3
// 6174.841 us; speedup vs baseline: 1.5906x; 1.5906x over previous
//
#include <hip/hip_runtime.h>

// Sinkhorn-log barycentric mapping, N=M=8192, D=128, reg=0.05, 50 iters.
// d_out layout: [ mapped: N*D f32 | pi: N*M f32 ].
// Mr = -C/reg is materialized in the pi region (overwritten by pi at the end).
// Fast path (ws_size >= 128 KB): u,v,xx,yy in d_ws; part in the mapped region
// (dead before the final fused pi+mapped kernel writes mapped).
// Slow path: everything in d_out scratch, separate k_pi + k_mapped.

#define NN 8192
#define MMX 8192
#define DD 128
#define NITER 50
#define LOGAB (-9.0109133472792881f)   /* log(1/8192) = -13*ln2 */
#define NEG20 (-20.0f)                 /* -1/reg */

static __device__ __forceinline__ void lse_acc(float& m, float& s, float x) {
    float mn = fmaxf(m, x);
    s = s * __expf(m - mn) + __expf(x - mn);
    m = mn;
}
static __device__ __forceinline__ void lse_merge(float& m, float& s, float m2, float s2) {
    float mn = fmaxf(m, m2);
    s = s * __expf(m - mn) + s2 * __expf(m2 - mn);
    m = mn;
}
static __device__ __forceinline__ void lse_acc4(float4& m, float4& s, float4 x) {
    lse_acc(m.x, s.x, x.x);
    lse_acc(m.y, s.y, x.y);
    lse_acc(m.z, s.z, x.z);
    lse_acc(m.w, s.w, x.w);
}
static __device__ __forceinline__ int swz(int r, int k) {
    // XOR word-column by row bits 3..5: b128 reads of rows 8 apart spread banks
    return k ^ (((r >> 3) & 7) << 2);
}

// ---- zero u, v --------------------------------------------------------------
__global__ void k_init(float* u, float* v) {
    int i = blockIdx.x * 1024 + threadIdx.x;
    if (i < 8192) { u[i] = 0.0f; v[i] = 0.0f; }
}

// ---- squared norms: one wave per row ---------------------------------------
__global__ __launch_bounds__(64) void k_sqnorm(const float* __restrict__ XP,
                                               const float* __restrict__ XQ,
                                               float* __restrict__ xx,
                                               float* __restrict__ yy) {
    int row = blockIdx.x;
    int lane = threadIdx.x;
    const float* src = (row < NN) ? (XP + (size_t)row * DD)
                                  : (XQ + (size_t)(row - NN) * DD);
    float2 w = *(const float2*)&src[lane * 2];
    float sres = w.x * w.x + w.y * w.y;
    #pragma unroll
    for (int off = 32; off > 0; off >>= 1)
        sres += __shfl_down(sres, off, 64);
    if (lane == 0) {
        if (row < NN) xx[row] = sres;
        else          yy[row - NN] = sres;
    }
}

// ---- Mr = -20 * max(0, xx + yy - 2 XP.XQ^T) --------------------------------
// 128x128 tile, K staged in two 64-wide chunks: 64 KB LDS -> 2 blocks/CU.
__global__ __launch_bounds__(256) void k_gemm_mr(const float* __restrict__ XP,
                                                 const float* __restrict__ XQ,
                                                 const float* __restrict__ xx,
                                                 const float* __restrict__ yy,
                                                 float* __restrict__ Mr) {
    __shared__ float As[128][64];
    __shared__ float Bs[128][64];
    int rb = blockIdx.y * 128, cb = blockIdx.x * 128;
    int t = threadIdx.x;
    int ty = t >> 4, tx = t & 15;
    int r0 = ty * 8, c0 = tx * 8;
    float acc[8][8] = {};

    for (int kc = 0; kc < 128; kc += 64) {
        __syncthreads();               // previous chunk's reads done
        #pragma unroll
        for (int i = 0; i < 8; ++i) {
            int f = i * 256 + t;       // 0..2047 float4 slots
            int r = f >> 4;            // 16 float4 per row
            int k4 = (f & 15) * 4;
            *(float4*)&As[r][swz(r, k4)] = *(const float4*)&XP[(size_t)(rb + r) * DD + kc + k4];
            *(float4*)&Bs[r][swz(r, k4)] = *(const float4*)&XQ[(size_t)(cb + r) * DD + kc + k4];
        }
        __syncthreads();
        for (int k = 0; k < 64; k += 4) {
            float4 a[8], b[8];
            #pragma unroll
            for (int i = 0; i < 8; ++i) {
                a[i] = *(float4*)&As[r0 + i][swz(r0 + i, k)];
                b[i] = *(float4*)&Bs[c0 + i][swz(c0 + i, k)];
            }
            #pragma unroll
            for (int i = 0; i < 8; ++i)
                #pragma unroll
                for (int j = 0; j < 8; ++j)
                    acc[i][j] += a[i].x * b[j].x + a[i].y * b[j].y +
                                 a[i].z * b[j].z + a[i].w * b[j].w;
        }
    }

    float yv[8];
    *(float4*)&yv[0] = *(const float4*)&yy[cb + c0];
    *(float4*)&yv[4] = *(const float4*)&yy[cb + c0 + 4];
    #pragma unroll
    for (int i = 0; i < 8; ++i) {
        int gr = rb + r0 + i;
        float xxi = xx[gr];
        float4 o0, o1;
        o0.x = NEG20 * fmaxf(xxi + yv[0] - 2.f * acc[i][0], 0.f);
        o0.y = NEG20 * fmaxf(xxi + yv[1] - 2.f * acc[i][1], 0.f);
        o0.z = NEG20 * fmaxf(xxi + yv[2] - 2.f * acc[i][2], 0.f);
        o0.w = NEG20 * fmaxf(xxi + yv[3] - 2.f * acc[i][3], 0.f);
        o1.x = NEG20 * fmaxf(xxi + yv[4] - 2.f * acc[i][4], 0.f);
        o1.y = NEG20 * fmaxf(xxi + yv[5] - 2.f * acc[i][5], 0.f);
        o1.z = NEG20 * fmaxf(xxi + yv[6] - 2.f * acc[i][6], 0.f);
        o1.w = NEG20 * fmaxf(xxi + yv[7] - 2.f * acc[i][7], 0.f);
        *(float4*)&Mr[(size_t)gr * MMX + cb + c0] = o0;
        *(float4*)&Mr[(size_t)gr * MMX + cb + c0 + 4] = o1;
    }
}

// ---- column-LSE partial: block = 1024 cols x 128 rows (no atomics) ----------
__global__ __launch_bounds__(256) void k_colpass(const float* __restrict__ Mr,
                                                 const float* __restrict__ u,
                                                 float* __restrict__ part) {
    int c = blockIdx.x * 1024 + threadIdx.x * 4;
    int n0 = blockIdx.y * 128;
    float4 mx = make_float4(-1e30f, -1e30f, -1e30f, -1e30f);
    float4 s = make_float4(0.f, 0.f, 0.f, 0.f);
    #pragma unroll 8
    for (int r = 0; r < 128; ++r) {
        float un = u[n0 + r];
        float4 w = *(const float4*)&Mr[(size_t)(n0 + r) * MMX + c];
        w.x += un; w.y += un; w.z += un; w.w += un;
        lse_acc4(mx, s, w);
    }
    float4 o;
    o.x = mx.x + __logf(s.x);
    o.y = mx.y + __logf(s.y);
    o.z = mx.z + __logf(s.z);
    o.w = mx.w + __logf(s.w);
    *(float4*)&part[(size_t)blockIdx.y * MMX + c] = o;
}

// ---- combine 64 chunk-LSEs -> v[m] -----------------------------------------
__global__ __launch_bounds__(256) void k_colcombine(const float* __restrict__ part,
                                                    float* __restrict__ v) {
    int m = blockIdx.x * 256 + threadIdx.x;
    float mx = -1e30f, s = 0.f;
    #pragma unroll 8
    for (int ch = 0; ch < 64; ++ch)
        lse_acc(mx, s, part[(size_t)ch * MMX + m]);
    v[m] = LOGAB - (mx + __logf(s));
}

// ---- row-LSE: block = 8 rows (v reload amortized 8x) ------------------------
__global__ __launch_bounds__(256) void k_rowpass(const float* __restrict__ Mr,
                                                 const float* __restrict__ v,
                                                 float* __restrict__ u) {
    int n0 = blockIdx.x * 8;
    int t = threadIdx.x;
    float4 mx[8], s[8];
    #pragma unroll
    for (int r = 0; r < 8; ++r) {
        mx[r] = make_float4(-1e30f, -1e30f, -1e30f, -1e30f);
        s[r] = make_float4(0.f, 0.f, 0.f, 0.f);
    }
    const float4* v4 = (const float4*)v;
    for (int i = t; i < MMX / 4; i += 256) {
        float4 vv = v4[i];
        #pragma unroll
        for (int r = 0; r < 8; ++r) {
            float4 w = *(const float4*)&Mr[(size_t)(n0 + r) * MMX + i * 4];
            w.x += vv.x; w.y += vv.y; w.z += vv.z; w.w += vv.w;
            lse_acc4(mx[r], s[r], w);
        }
    }
    __shared__ float smm[8][4], sss[8][4];
    int wid = t >> 6, lane = t & 63;
    #pragma unroll
    for (int r = 0; r < 8; ++r) {
        float m1 = mx[r].x, s1 = s[r].x;
        lse_merge(m1, s1, mx[r].y, s[r].y);
        lse_merge(m1, s1, mx[r].z, s[r].z);
        lse_merge(m1, s1, mx[r].w, s[r].w);
        #pragma unroll
        for (int off = 32; off > 0; off >>= 1) {
            float m2 = __shfl_xor(m1, off);
            float s2 = __shfl_xor(s1, off);
            lse_merge(m1, s1, m2, s2);
        }
        if (lane == 0) { smm[r][wid] = m1; sss[r][wid] = s1; }
    }
    __syncthreads();
    if (t < 8) {
        float m1 = smm[t][0], s1 = sss[t][0];
        lse_merge(m1, s1, smm[t][1], sss[t][1]);
        lse_merge(m1, s1, smm[t][2], sss[t][2]);
        lse_merge(m1, s1, smm[t][3], sss[t][3]);
        u[n0 + t] = LOGAB - (m1 + __logf(s1));
    }
}

// ---- FUSED: pi = exp(Mr+u+v) (in place) AND mapped = 8192 * pi @ XQ ---------
// grid 256 (32-row strips), 512 threads. Thread-tile 4r x 4d, 2-way k-split.
__global__ __launch_bounds__(512, 1) void k_pi_mapped(float* __restrict__ P,
                                                      const float* __restrict__ XQ,
                                                      const float* __restrict__ u,
                                                      const float* __restrict__ v,
                                                      float* __restrict__ mapped) {
    __shared__ float PIs[32][68];      // +4 pad
    __shared__ float QS[64][128];      // reused for the acc merge
    int r0 = blockIdx.x * 32;
    int t = threadIdx.x;               // 0..511
    int tid = t & 255;
    int half = t >> 8;
    int rg = tid >> 5;                 // 0..7
    int dg = tid & 31;                 // 0..31
    int prow = t >> 4;                 // pi-stage row (0..31)
    int pc4 = (t & 15) * 4;            // pi-stage col
    int qrb = t >> 5;                  // XQ-stage row base
    int qc4 = (t & 31) * 4;            // XQ-stage col
    float urow = u[r0 + prow];

    float4 acc[4];
    acc[0] = acc[1] = acc[2] = acc[3] = make_float4(0.f, 0.f, 0.f, 0.f);

    float4 pw, vv, xq0, xq1, xq2, xq3;
    pw = *(const float4*)&P[(size_t)(r0 + prow) * MMX + pc4];
    vv = *(const float4*)&v[pc4];
    xq0 = *(const float4*)&XQ[(size_t)(qrb) * DD + qc4];
    xq1 = *(const float4*)&XQ[(size_t)(16 + qrb) * DD + qc4];
    xq2 = *(const float4*)&XQ[(size_t)(32 + qrb) * DD + qc4];
    xq3 = *(const float4*)&XQ[(size_t)(48 + qrb) * DD + qc4];

    for (int mb = 0; mb < MMX; mb += 64) {
        __syncthreads();
        float4 w;
        w.x = __expf(pw.x + urow + vv.x);
        w.y = __expf(pw.y + urow + vv.y);
        w.z = __expf(pw.z + urow + vv.z);
        w.w = __expf(pw.w + urow + vv.w);
        *(float4*)&PIs[prow][pc4] = w;
        *(float4*)&QS[qrb][qc4] = xq0;
        *(float4*)&QS[16 + qrb][qc4] = xq1;
        *(float4*)&QS[32 + qrb][qc4] = xq2;
        *(float4*)&QS[48 + qrb][qc4] = xq3;
        __syncthreads();
        *(float4*)&P[(size_t)(r0 + prow) * MMX + mb + pc4] = w;
        if (mb + 64 < MMX) {
            int nb = mb + 64;
            pw = *(const float4*)&P[(size_t)(r0 + prow) * MMX + nb + pc4];
            vv = *(const float4*)&v[nb + pc4];
            xq0 = *(const float4*)&XQ[(size_t)(nb + qrb) * DD + qc4];
            xq1 = *(const float4*)&XQ[(size_t)(nb + 16 + qrb) * DD + qc4];
            xq2 = *(const float4*)&XQ[(size_t)(nb + 32 + qrb) * DD + qc4];
            xq3 = *(const float4*)&XQ[(size_t)(nb + 48 + qrb) * DD + qc4];
        }
        #pragma unroll
        for (int sstep = 0; sstep < 8; ++sstep) {
            int k = (half * 8 + sstep) * 4;
            float4 q0 = *(float4*)&QS[k + 0][dg * 4];
            float4 q1 = *(float4*)&QS[k + 1][dg * 4];
            float4 q2 = *(float4*)&QS[k + 2][dg * 4];
            float4 q3 = *(float4*)&QS[k + 3][dg * 4];
            #pragma unroll
            for (int j = 0; j < 4; ++j) {
                float4 p = *(float4*)&PIs[rg * 4 + j][k];
                acc[j].x += p.x * q0.x + p.y * q1.x + p.z * q2.x + p.w * q3.x;
                acc[j].y += p.x * q0.y + p.y * q1.y + p.z * q2.y + p.w * q3.y;
                acc[j].z += p.x * q0.z + p.y * q1.z + p.z * q2.z + p.w * q3.z;
                acc[j].w += p.x * q0.w + p.y * q1.w + p.z * q2.w + p.w * q3.w;
            }
        }
    }
    __syncthreads();
    float* mrg = &QS[0][0];
    if (half == 1) {
        #pragma unroll
        for (int j = 0; j < 4; ++j)
            *(float4*)&mrg[tid * 16 + j * 4] = acc[j];
    }
    __syncthreads();
    if (half == 0) {
        #pragma unroll
        for (int j = 0; j < 4; ++j) {
            float4 o = *(const float4*)&mrg[tid * 16 + j * 4];
            o.x = (acc[j].x + o.x) * 8192.f;
            o.y = (acc[j].y + o.y) * 8192.f;
            o.z = (acc[j].z + o.z) * 8192.f;
            o.w = (acc[j].w + o.w) * 8192.f;
            *(float4*)&mapped[(size_t)(r0 + rg * 4 + j) * DD + dg * 4] = o;
        }
    }
}

// ---- fallback path (ws too small): separate pi / mapped ---------------------
__global__ __launch_bounds__(256) void k_pi(float* __restrict__ Mr,
                                            const float* __restrict__ u,
                                            const float* __restrict__ v) {
    const float4* v4 = (const float4*)v;
    for (int i = blockIdx.x * 256 + threadIdx.x; i < NN * MMX / 4; i += 2048 * 256) {
        int n = i >> 11;
        int m4 = i & 2047;
        float un = u[n];
        float4 vv = v4[m4];
        float4* p = (float4*)Mr + i;
        float4 w = *p;
        w.x = __expf(w.x + un + vv.x);
        w.y = __expf(w.y + un + vv.y);
        w.z = __expf(w.z + un + vv.z);
        w.w = __expf(w.w + un + vv.w);
        *p = w;
    }
}

__global__ __launch_bounds__(256) void k_mapped(const float* __restrict__ pi,
                                                const float* __restrict__ XQ,
                                                float* __restrict__ mapped) {
    __shared__ float XQs[64][128];
    __shared__ float PIs[32][64];
    int r0 = blockIdx.x * 32;
    int t = threadIdx.x;
    int dg = (t & 31) * 4;
    int rg = (t >> 5) * 4;
    float4 acc[4];
    #pragma unroll
    for (int j = 0; j < 4; ++j) acc[j] = make_float4(0.f, 0.f, 0.f, 0.f);

    for (int mb = 0; mb < MMX; mb += 64) {
        __syncthreads();
        #pragma unroll
        for (int i = 0; i < 8; ++i) {
            int f = i * 256 + t;
            int rr = f >> 5;
            int k4 = (f & 31) * 4;
            *(float4*)&XQs[rr][k4] = *(const float4*)&XQ[(size_t)(mb + rr) * DD + k4];
        }
        #pragma unroll
        for (int i = 0; i < 2; ++i) {
            int f = i * 256 + t;
            int rr = f >> 4;
            int c4 = (f & 15) * 4;
            *(float4*)&PIs[rr][c4] = *(const float4*)&pi[(size_t)(r0 + rr) * MMX + mb + c4];
        }
        __syncthreads();
        for (int mm = 0; mm < 64; mm += 4) {
            float4 q0 = *(float4*)&XQs[mm + 0][dg];
            float4 q1 = *(float4*)&XQs[mm + 1][dg];
            float4 q2 = *(float4*)&XQs[mm + 2][dg];
            float4 q3 = *(float4*)&XQs[mm + 3][dg];
            #pragma unroll
            for (int j = 0; j < 4; ++j) {
                float4 p = *(float4*)&PIs[rg + j][mm];
                acc[j].x += p.x * q0.x + p.y * q1.x + p.z * q2.x + p.w * q3.x;
                acc[j].y += p.x * q0.y + p.y * q1.y + p.z * q2.y + p.w * q3.y;
                acc[j].z += p.x * q0.z + p.y * q1.z + p.z * q2.z + p.w * q3.z;
                acc[j].w += p.x * q0.w + p.y * q1.w + p.z * q2.w + p.w * q3.w;
            }
        }
    }
    #pragma unroll
    for (int j = 0; j < 4; ++j) {
        float4 o = acc[j];
        o.x *= 8192.f; o.y *= 8192.f; o.z *= 8192.f; o.w *= 8192.f;
        *(float4*)&mapped[(size_t)(r0 + rg + j) * DD + dg] = o;
    }
}

extern "C" void kernel_launch(void* const* d_in, const int* in_sizes, int n_in,
                              void* d_out, int out_size, void* d_ws, size_t ws_size,
                              hipStream_t stream) {
    const float* XP = (const float*)d_in[0];
    const float* XQ = (const float*)d_in[1];
    float* out = (float*)d_out;
    float* Mr = out + (size_t)NN * DD;            // pi region: Mr then pi
    float* part = out + 65536;                    // 64 x 8192 partials (2 MiB)

    bool fast = (ws_size >= 131072);
    float* u  = fast ? (float*)d_ws           : out;
    float* v  = fast ? (float*)d_ws + 8192    : out + 8192;
    float* xx = fast ? (float*)d_ws + 16384   : out + 40960;
    float* yy = fast ? (float*)d_ws + 24576   : out + 49152;

    k_init<<<8, 1024, 0, stream>>>(u, v);
    k_sqnorm<<<NN + MMX, 64, 0, stream>>>(XP, XQ, xx, yy);
    k_gemm_mr<<<dim3(64, 64), 256, 0, stream>>>(XP, XQ, xx, yy, Mr);

    for (int it = 0; it < NITER; ++it) {
        k_colpass<<<dim3(8, 64), 256, 0, stream>>>(Mr, u, part);
        k_colcombine<<<32, 256, 0, stream>>>(part, v);
        k_rowpass<<<1024, 256, 0, stream>>>(Mr, v, u);
    }

    if (fast) {
        k_pi_mapped<<<256, 512, 0, stream>>>(Mr, XQ, u, v, out);
    } else {
        k_pi<<<2048, 256, 0, stream>>>(Mr, u, v);
        k_mapped<<<256, 256, 0, stream>>>(Mr, XQ, out);
    }
}

// Round 4
// 6021.302 us; speedup vs baseline: 1.6312x; 1.0255x over previous
//
#include <hip/hip_runtime.h>

// Sinkhorn-log barycentric mapping, N=M=8192, D=128, reg=0.05, 50 iters.
// d_out layout: [ mapped: N*D f32 | pi: N*M f32 ].
// Mr = -C/reg is materialized in the pi region (overwritten by pi at the end).
// part lives at out+65536 (2 MiB, inside mapped region; dead before mapped is
// written). u,v,xx,yy in d_ws when available. When ws >= 2.2 MiB, a bf16
// transposed copy XQT[128][8192] of XQ lives in ws and the final fused
// pi+mapped kernel uses MFMA; otherwise the round-3 vector version runs.

#define NN 8192
#define MMX 8192
#define DD 128
#define NITER 50
#define LOGAB (-9.0109133472792881f)   /* log(1/8192) = -13*ln2 */
#define NEG20 (-20.0f)                 /* -1/reg */

typedef short bf16x8 __attribute__((ext_vector_type(8)));
typedef float f32x4 __attribute__((ext_vector_type(4)));

static __device__ __forceinline__ void lse_acc(float& m, float& s, float x) {
    float mn = fmaxf(m, x);
    s = s * __expf(m - mn) + __expf(x - mn);
    m = mn;
}
static __device__ __forceinline__ void lse_merge(float& m, float& s, float m2, float s2) {
    float mn = fmaxf(m, m2);
    s = s * __expf(m - mn) + s2 * __expf(m2 - mn);
    m = mn;
}
static __device__ __forceinline__ void lse_acc4(float4& m, float4& s, float4 x) {
    lse_acc(m.x, s.x, x.x);
    lse_acc(m.y, s.y, x.y);
    lse_acc(m.z, s.z, x.z);
    lse_acc(m.w, s.w, x.w);
}
static __device__ __forceinline__ int swz(int r, int k) {
    return k ^ (((r >> 3) & 7) << 2);
}
static __device__ __forceinline__ unsigned f2bf(float x) {
    unsigned u = __float_as_uint(x);
    return (u + 0x7FFF + ((u >> 16) & 1)) >> 16;   // RNE
}

// ---- zero u, v --------------------------------------------------------------
__global__ void k_init(float* u, float* v) {
    int i = blockIdx.x * 1024 + threadIdx.x;
    if (i < 8192) { u[i] = 0.0f; v[i] = 0.0f; }
}

// ---- squared norms: one wave per row ---------------------------------------
__global__ __launch_bounds__(64) void k_sqnorm(const float* __restrict__ XP,
                                               const float* __restrict__ XQ,
                                               float* __restrict__ xx,
                                               float* __restrict__ yy) {
    int row = blockIdx.x;
    int lane = threadIdx.x;
    const float* src = (row < NN) ? (XP + (size_t)row * DD)
                                  : (XQ + (size_t)(row - NN) * DD);
    float2 w = *(const float2*)&src[lane * 2];
    float sres = w.x * w.x + w.y * w.y;
    #pragma unroll
    for (int off = 32; off > 0; off >>= 1)
        sres += __shfl_down(sres, off, 64);
    if (lane == 0) {
        if (row < NN) xx[row] = sres;
        else          yy[row - NN] = sres;
    }
}

// ---- XQT[d][m] = bf16(XQ[m][d]), once ---------------------------------------
__global__ __launch_bounds__(256) void k_xqt(const float* __restrict__ XQ,
                                             unsigned* __restrict__ XQT32) {
    __shared__ float As[32][129];
    int mb = blockIdx.x * 32;
    int t = threadIdx.x;
    int r = t >> 3, c0 = (t & 7) * 16;
    #pragma unroll
    for (int j = 0; j < 4; ++j)
        *(float4*)&As[r][c0 + j * 4] = *(const float4*)&XQ[(size_t)(mb + r) * DD + c0 + j * 4];
    __syncthreads();
    int d = t >> 1, p0 = (t & 1) * 8;
    #pragma unroll
    for (int j = 0; j < 8; ++j) {
        int pp = p0 + j;
        unsigned lo = f2bf(As[2 * pp][d]);
        unsigned hi = f2bf(As[2 * pp + 1][d]);
        XQT32[(size_t)d * 4096 + (mb >> 1) + pp] = lo | (hi << 16);
    }
}

// ---- Mr = -20 * max(0, xx + yy - 2 XP.XQ^T) --------------------------------
__global__ __launch_bounds__(256) void k_gemm_mr(const float* __restrict__ XP,
                                                 const float* __restrict__ XQ,
                                                 const float* __restrict__ xx,
                                                 const float* __restrict__ yy,
                                                 float* __restrict__ Mr) {
    __shared__ float As[128][64];
    __shared__ float Bs[128][64];
    int rb = blockIdx.y * 128, cb = blockIdx.x * 128;
    int t = threadIdx.x;
    int ty = t >> 4, tx = t & 15;
    int r0 = ty * 8, c0 = tx * 8;
    float acc[8][8] = {};

    for (int kc = 0; kc < 128; kc += 64) {
        __syncthreads();
        #pragma unroll
        for (int i = 0; i < 8; ++i) {
            int f = i * 256 + t;
            int r = f >> 4;
            int k4 = (f & 15) * 4;
            *(float4*)&As[r][swz(r, k4)] = *(const float4*)&XP[(size_t)(rb + r) * DD + kc + k4];
            *(float4*)&Bs[r][swz(r, k4)] = *(const float4*)&XQ[(size_t)(cb + r) * DD + kc + k4];
        }
        __syncthreads();
        for (int k = 0; k < 64; k += 4) {
            float4 a[8], b[8];
            #pragma unroll
            for (int i = 0; i < 8; ++i) {
                a[i] = *(float4*)&As[r0 + i][swz(r0 + i, k)];
                b[i] = *(float4*)&Bs[c0 + i][swz(c0 + i, k)];
            }
            #pragma unroll
            for (int i = 0; i < 8; ++i)
                #pragma unroll
                for (int j = 0; j < 8; ++j)
                    acc[i][j] += a[i].x * b[j].x + a[i].y * b[j].y +
                                 a[i].z * b[j].z + a[i].w * b[j].w;
        }
    }

    float yv[8];
    *(float4*)&yv[0] = *(const float4*)&yy[cb + c0];
    *(float4*)&yv[4] = *(const float4*)&yy[cb + c0 + 4];
    #pragma unroll
    for (int i = 0; i < 8; ++i) {
        int gr = rb + r0 + i;
        float xxi = xx[gr];
        float4 o0, o1;
        o0.x = NEG20 * fmaxf(xxi + yv[0] - 2.f * acc[i][0], 0.f);
        o0.y = NEG20 * fmaxf(xxi + yv[1] - 2.f * acc[i][1], 0.f);
        o0.z = NEG20 * fmaxf(xxi + yv[2] - 2.f * acc[i][2], 0.f);
        o0.w = NEG20 * fmaxf(xxi + yv[3] - 2.f * acc[i][3], 0.f);
        o1.x = NEG20 * fmaxf(xxi + yv[4] - 2.f * acc[i][4], 0.f);
        o1.y = NEG20 * fmaxf(xxi + yv[5] - 2.f * acc[i][5], 0.f);
        o1.z = NEG20 * fmaxf(xxi + yv[6] - 2.f * acc[i][6], 0.f);
        o1.w = NEG20 * fmaxf(xxi + yv[7] - 2.f * acc[i][7], 0.f);
        *(float4*)&Mr[(size_t)gr * MMX + cb + c0] = o0;
        *(float4*)&Mr[(size_t)gr * MMX + cb + c0 + 4] = o1;
    }
}

// ---- column-LSE partial, 4 blocks/CU: block = 512 cols x 128 rows ------------
__global__ __launch_bounds__(256) void k_colpass2(const float* __restrict__ Mr,
                                                  const float* __restrict__ u,
                                                  float* __restrict__ part) {
    int c = blockIdx.x * 512 + threadIdx.x * 2;
    int n0 = blockIdx.y * 128;
    float2 mx = make_float2(-1e30f, -1e30f);
    float2 s = make_float2(0.f, 0.f);
    #pragma unroll 8
    for (int r = 0; r < 128; ++r) {
        float un = u[n0 + r];
        float2 w = *(const float2*)&Mr[(size_t)(n0 + r) * MMX + c];
        lse_acc(mx.x, s.x, w.x + un);
        lse_acc(mx.y, s.y, w.y + un);
    }
    float2 o;
    o.x = mx.x + __logf(s.x);
    o.y = mx.y + __logf(s.y);
    *(float2*)&part[(size_t)blockIdx.y * MMX + c] = o;
}

// ---- old colpass (small-ws path) --------------------------------------------
__global__ __launch_bounds__(256) void k_colpass(const float* __restrict__ Mr,
                                                 const float* __restrict__ u,
                                                 float* __restrict__ part) {
    int c = blockIdx.x * 1024 + threadIdx.x * 4;
    int n0 = blockIdx.y * 128;
    float4 mx = make_float4(-1e30f, -1e30f, -1e30f, -1e30f);
    float4 s = make_float4(0.f, 0.f, 0.f, 0.f);
    #pragma unroll 8
    for (int r = 0; r < 128; ++r) {
        float un = u[n0 + r];
        float4 w = *(const float4*)&Mr[(size_t)(n0 + r) * MMX + c];
        w.x += un; w.y += un; w.z += un; w.w += un;
        lse_acc4(mx, s, w);
    }
    float4 o;
    o.x = mx.x + __logf(s.x);
    o.y = mx.y + __logf(s.y);
    o.z = mx.z + __logf(s.z);
    o.w = mx.w + __logf(s.w);
    *(float4*)&part[(size_t)blockIdx.y * MMX + c] = o;
}

// ---- combine 64 chunk-LSEs -> v[m] -----------------------------------------
__global__ __launch_bounds__(256) void k_colcombine(const float* __restrict__ part,
                                                    float* __restrict__ v) {
    int m = blockIdx.x * 256 + threadIdx.x;
    float mx = -1e30f, s = 0.f;
    #pragma unroll 8
    for (int ch = 0; ch < 64; ++ch)
        lse_acc(mx, s, part[(size_t)ch * MMX + m]);
    v[m] = LOGAB - (mx + __logf(s));
}

// ---- row-LSE: block = 8 rows ------------------------------------------------
__global__ __launch_bounds__(256) void k_rowpass(const float* __restrict__ Mr,
                                                 const float* __restrict__ v,
                                                 float* __restrict__ u) {
    int n0 = blockIdx.x * 8;
    int t = threadIdx.x;
    float4 mx[8], s[8];
    #pragma unroll
    for (int r = 0; r < 8; ++r) {
        mx[r] = make_float4(-1e30f, -1e30f, -1e30f, -1e30f);
        s[r] = make_float4(0.f, 0.f, 0.f, 0.f);
    }
    const float4* v4 = (const float4*)v;
    for (int i = t; i < MMX / 4; i += 256) {
        float4 vv = v4[i];
        #pragma unroll
        for (int r = 0; r < 8; ++r) {
            float4 w = *(const float4*)&Mr[(size_t)(n0 + r) * MMX + i * 4];
            w.x += vv.x; w.y += vv.y; w.z += vv.z; w.w += vv.w;
            lse_acc4(mx[r], s[r], w);
        }
    }
    __shared__ float smm[8][4], sss[8][4];
    int wid = t >> 6, lane = t & 63;
    #pragma unroll
    for (int r = 0; r < 8; ++r) {
        float m1 = mx[r].x, s1 = s[r].x;
        lse_merge(m1, s1, mx[r].y, s[r].y);
        lse_merge(m1, s1, mx[r].z, s[r].z);
        lse_merge(m1, s1, mx[r].w, s[r].w);
        #pragma unroll
        for (int off = 32; off > 0; off >>= 1) {
            float m2 = __shfl_xor(m1, off);
            float s2 = __shfl_xor(s1, off);
            lse_merge(m1, s1, m2, s2);
        }
        if (lane == 0) { smm[r][wid] = m1; sss[r][wid] = s1; }
    }
    __syncthreads();
    if (t < 8) {
        float m1 = smm[t][0], s1 = sss[t][0];
        lse_merge(m1, s1, smm[t][1], sss[t][1]);
        lse_merge(m1, s1, smm[t][2], sss[t][2]);
        lse_merge(m1, s1, smm[t][3], sss[t][3]);
        u[n0 + t] = LOGAB - (m1 + __logf(s1));
    }
}

// ---- MFMA FUSED: pi = exp(Mr+u+v) (in place) AND mapped = 8192 * pi @ XQ -----
// grid 256 (32-row strips) x 512 threads (8 waves). Per 64-m chunk:
// stage pi-bf16 [32][64] + XQT-chunk [128][64] in LDS (XOR-swizzled granules),
// then each wave does 4x mfma_f32_16x16x32_bf16 into 2 16x16 acc tiles.
__global__ __launch_bounds__(512, 1) void k_pi_mapped_mfma(float* __restrict__ P,
                                                           const unsigned* __restrict__ XQT32,
                                                           const float* __restrict__ u,
                                                           const float* __restrict__ v,
                                                           float* __restrict__ mapped) {
    __shared__ unsigned short PIs[32 * 64];    // row n: 8 granules(16B), g^=(n&7)
    __shared__ unsigned short QTs[128 * 64];   // row d: same swizzle
    int r0 = blockIdx.x * 32;
    int t = threadIdx.x;                 // 0..511
    int wid = t >> 6, lane = t & 63;
    int ntile = (wid >> 2) * 16;         // 0 | 16
    int dbase = (wid & 3) * 32;          // 0,32,64,96
    // pi pack mapping: 4 m's per thread
    int prow = t >> 4;                   // 0..31
    int pm4 = (t & 15) * 4;
    int pgran = (t & 15) >> 1, phalf = t & 1;
    // QT stage mapping: 16 bf16 (2 granules) per thread
    int qd = t >> 2;                     // 0..127
    int qg0 = (t & 3) * 2;
    float urow = u[r0 + prow];

    f32x4 acc[2];
    acc[0] = (f32x4)(0.f);
    acc[1] = (f32x4)(0.f);

    // prefetch chunk 0
    float4 pw = *(const float4*)&P[(size_t)(r0 + prow) * MMX + pm4];
    float4 vv = *(const float4*)&v[pm4];
    uint4 xa = *(const uint4*)&XQT32[(size_t)qd * 4096 + qg0 * 4];
    uint4 xb = *(const uint4*)&XQT32[(size_t)qd * 4096 + qg0 * 4 + 4];

    for (int mb = 0; mb < MMX; mb += 64) {
        __syncthreads();                 // previous chunk's LDS reads done
        float4 w;
        w.x = __expf(pw.x + urow + vv.x);
        w.y = __expf(pw.y + urow + vv.y);
        w.z = __expf(pw.z + urow + vv.z);
        w.w = __expf(pw.w + urow + vv.w);
        uint2 pk;
        pk.x = f2bf(w.x) | (f2bf(w.y) << 16);
        pk.y = f2bf(w.z) | (f2bf(w.w) << 16);
        *(uint2*)&PIs[prow * 64 + (((pgran ^ (prow & 7)) * 16 + phalf * 8) >> 1)] = pk;
        *(uint4*)&QTs[qd * 64 + (((qg0 ^ (qd & 7)) * 16) >> 1)] = xa;
        *(uint4*)&QTs[qd * 64 + ((((qg0 + 1) ^ (qd & 7)) * 16) >> 1)] = xb;
        __syncthreads();                 // staged
        *(float4*)&P[(size_t)(r0 + prow) * MMX + mb + pm4] = w;   // pi out
        if (mb + 64 < MMX) {
            int nb = mb + 64;
            pw = *(const float4*)&P[(size_t)(r0 + prow) * MMX + nb + pm4];
            vv = *(const float4*)&v[nb + pm4];
            xa = *(const uint4*)&XQT32[(size_t)qd * 4096 + (nb >> 1) + qg0 * 4];
            xb = *(const uint4*)&XQT32[(size_t)qd * 4096 + (nb >> 1) + qg0 * 4 + 4];
        }
        // MFMA: A row = ntile + (lane&15), k = ks*32 + (lane>>4)*8
        int arow = ntile + (lane & 15);
        bf16x8 afr[2];
        #pragma unroll
        for (int ks = 0; ks < 2; ++ks) {
            int g = ks * 4 + (lane >> 4);
            afr[ks] = *(bf16x8*)&PIs[arow * 64 + (((g ^ (arow & 7)) * 16) >> 1)];
        }
        #pragma unroll
        for (int dt = 0; dt < 2; ++dt) {
            int drow = dbase + dt * 16 + (lane & 15);
            #pragma unroll
            for (int ks = 0; ks < 2; ++ks) {
                int g = ks * 4 + (lane >> 4);
                bf16x8 bfr = *(bf16x8*)&QTs[drow * 64 + (((g ^ (drow & 7)) * 16) >> 1)];
                acc[dt] = __builtin_amdgcn_mfma_f32_16x16x32_bf16(afr[ks], bfr, acc[dt], 0, 0, 0);
            }
        }
    }
    // epilogue: D col = lane&15, row = (lane>>4)*4 + reg
    #pragma unroll
    for (int dt = 0; dt < 2; ++dt) {
        int dcol = dbase + dt * 16 + (lane & 15);
        #pragma unroll
        for (int reg = 0; reg < 4; ++reg) {
            int nrow = r0 + ntile + (lane >> 4) * 4 + reg;
            mapped[(size_t)nrow * DD + dcol] = acc[dt][reg] * 8192.f;
        }
    }
}

// ---- vector FUSED (mid-ws path, round-3 kernel) ------------------------------
__global__ __launch_bounds__(512, 1) void k_pi_mapped(float* __restrict__ P,
                                                      const float* __restrict__ XQ,
                                                      const float* __restrict__ u,
                                                      const float* __restrict__ v,
                                                      float* __restrict__ mapped) {
    __shared__ float PIs[32][68];
    __shared__ float QS[64][128];
    int r0 = blockIdx.x * 32;
    int t = threadIdx.x;
    int tid = t & 255;
    int half = t >> 8;
    int rg = tid >> 5;
    int dg = tid & 31;
    int prow = t >> 4;
    int pc4 = (t & 15) * 4;
    int qrb = t >> 5;
    int qc4 = (t & 31) * 4;
    float urow = u[r0 + prow];

    float4 acc[4];
    acc[0] = acc[1] = acc[2] = acc[3] = make_float4(0.f, 0.f, 0.f, 0.f);

    float4 pw, vv, xq0, xq1, xq2, xq3;
    pw = *(const float4*)&P[(size_t)(r0 + prow) * MMX + pc4];
    vv = *(const float4*)&v[pc4];
    xq0 = *(const float4*)&XQ[(size_t)(qrb) * DD + qc4];
    xq1 = *(const float4*)&XQ[(size_t)(16 + qrb) * DD + qc4];
    xq2 = *(const float4*)&XQ[(size_t)(32 + qrb) * DD + qc4];
    xq3 = *(const float4*)&XQ[(size_t)(48 + qrb) * DD + qc4];

    for (int mb = 0; mb < MMX; mb += 64) {
        __syncthreads();
        float4 w;
        w.x = __expf(pw.x + urow + vv.x);
        w.y = __expf(pw.y + urow + vv.y);
        w.z = __expf(pw.z + urow + vv.z);
        w.w = __expf(pw.w + urow + vv.w);
        *(float4*)&PIs[prow][pc4] = w;
        *(float4*)&QS[qrb][qc4] = xq0;
        *(float4*)&QS[16 + qrb][qc4] = xq1;
        *(float4*)&QS[32 + qrb][qc4] = xq2;
        *(float4*)&QS[48 + qrb][qc4] = xq3;
        __syncthreads();
        *(float4*)&P[(size_t)(r0 + prow) * MMX + mb + pc4] = w;
        if (mb + 64 < MMX) {
            int nb = mb + 64;
            pw = *(const float4*)&P[(size_t)(r0 + prow) * MMX + nb + pc4];
            vv = *(const float4*)&v[nb + pc4];
            xq0 = *(const float4*)&XQ[(size_t)(nb + qrb) * DD + qc4];
            xq1 = *(const float4*)&XQ[(size_t)(nb + 16 + qrb) * DD + qc4];
            xq2 = *(const float4*)&XQ[(size_t)(nb + 32 + qrb) * DD + qc4];
            xq3 = *(const float4*)&XQ[(size_t)(nb + 48 + qrb) * DD + qc4];
        }
        #pragma unroll
        for (int sstep = 0; sstep < 8; ++sstep) {
            int k = (half * 8 + sstep) * 4;
            float4 q0 = *(float4*)&QS[k + 0][dg * 4];
            float4 q1 = *(float4*)&QS[k + 1][dg * 4];
            float4 q2 = *(float4*)&QS[k + 2][dg * 4];
            float4 q3 = *(float4*)&QS[k + 3][dg * 4];
            #pragma unroll
            for (int j = 0; j < 4; ++j) {
                float4 p = *(float4*)&PIs[rg * 4 + j][k];
                acc[j].x += p.x * q0.x + p.y * q1.x + p.z * q2.x + p.w * q3.x;
                acc[j].y += p.x * q0.y + p.y * q1.y + p.z * q2.y + p.w * q3.y;
                acc[j].z += p.x * q0.z + p.y * q1.z + p.z * q2.z + p.w * q3.z;
                acc[j].w += p.x * q0.w + p.y * q1.w + p.z * q2.w + p.w * q3.w;
            }
        }
    }
    __syncthreads();
    float* mrg = &QS[0][0];
    if (half == 1) {
        #pragma unroll
        for (int j = 0; j < 4; ++j)
            *(float4*)&mrg[tid * 16 + j * 4] = acc[j];
    }
    __syncthreads();
    if (half == 0) {
        #pragma unroll
        for (int j = 0; j < 4; ++j) {
            float4 o = *(const float4*)&mrg[tid * 16 + j * 4];
            o.x = (acc[j].x + o.x) * 8192.f;
            o.y = (acc[j].y + o.y) * 8192.f;
            o.z = (acc[j].z + o.z) * 8192.f;
            o.w = (acc[j].w + o.w) * 8192.f;
            *(float4*)&mapped[(size_t)(r0 + rg * 4 + j) * DD + dg * 4] = o;
        }
    }
}

// ---- fallback (tiny ws): separate pi / mapped --------------------------------
__global__ __launch_bounds__(256) void k_pi(float* __restrict__ Mr,
                                            const float* __restrict__ u,
                                            const float* __restrict__ v) {
    const float4* v4 = (const float4*)v;
    for (int i = blockIdx.x * 256 + threadIdx.x; i < NN * MMX / 4; i += 2048 * 256) {
        int n = i >> 11;
        int m4 = i & 2047;
        float un = u[n];
        float4 vv = v4[m4];
        float4* p = (float4*)Mr + i;
        float4 w = *p;
        w.x = __expf(w.x + un + vv.x);
        w.y = __expf(w.y + un + vv.y);
        w.z = __expf(w.z + un + vv.z);
        w.w = __expf(w.w + un + vv.w);
        *p = w;
    }
}

__global__ __launch_bounds__(256) void k_mapped(const float* __restrict__ pi,
                                                const float* __restrict__ XQ,
                                                float* __restrict__ mapped) {
    __shared__ float XQs[64][128];
    __shared__ float PIs[32][64];
    int r0 = blockIdx.x * 32;
    int t = threadIdx.x;
    int dg = (t & 31) * 4;
    int rg = (t >> 5) * 4;
    float4 acc[4];
    #pragma unroll
    for (int j = 0; j < 4; ++j) acc[j] = make_float4(0.f, 0.f, 0.f, 0.f);

    for (int mb = 0; mb < MMX; mb += 64) {
        __syncthreads();
        #pragma unroll
        for (int i = 0; i < 8; ++i) {
            int f = i * 256 + t;
            int rr = f >> 5;
            int k4 = (f & 31) * 4;
            *(float4*)&XQs[rr][k4] = *(const float4*)&XQ[(size_t)(mb + rr) * DD + k4];
        }
        #pragma unroll
        for (int i = 0; i < 2; ++i) {
            int f = i * 256 + t;
            int rr = f >> 4;
            int c4 = (f & 15) * 4;
            *(float4*)&PIs[rr][c4] = *(const float4*)&pi[(size_t)(r0 + rr) * MMX + mb + c4];
        }
        __syncthreads();
        for (int mm = 0; mm < 64; mm += 4) {
            float4 q0 = *(float4*)&XQs[mm + 0][dg];
            float4 q1 = *(float4*)&XQs[mm + 1][dg];
            float4 q2 = *(float4*)&XQs[mm + 2][dg];
            float4 q3 = *(float4*)&XQs[mm + 3][dg];
            #pragma unroll
            for (int j = 0; j < 4; ++j) {
                float4 p = *(float4*)&PIs[rg + j][mm];
                acc[j].x += p.x * q0.x + p.y * q1.x + p.z * q2.x + p.w * q3.x;
                acc[j].y += p.x * q0.y + p.y * q1.y + p.z * q2.y + p.w * q3.y;
                acc[j].z += p.x * q0.z + p.y * q1.z + p.z * q2.z + p.w * q3.z;
                acc[j].w += p.x * q0.w + p.y * q1.w + p.z * q2.w + p.w * q3.w;
            }
        }
    }
    #pragma unroll
    for (int j = 0; j < 4; ++j) {
        float4 o = acc[j];
        o.x *= 8192.f; o.y *= 8192.f; o.z *= 8192.f; o.w *= 8192.f;
        *(float4*)&mapped[(size_t)(r0 + rg + j) * DD + dg] = o;
    }
}

extern "C" void kernel_launch(void* const* d_in, const int* in_sizes, int n_in,
                              void* d_out, int out_size, void* d_ws, size_t ws_size,
                              hipStream_t stream) {
    const float* XP = (const float*)d_in[0];
    const float* XQ = (const float*)d_in[1];
    float* out = (float*)d_out;
    float* Mr = out + (size_t)NN * DD;            // pi region: Mr then pi
    float* part = out + 65536;                    // 64 x 8192 partials (2 MiB)

    bool big = (ws_size >= 2228224);              // XQT(2 MiB) + u/v/xx/yy
    bool mid = (ws_size >= 131072);
    unsigned* XQT32 = big ? (unsigned*)d_ws : nullptr;
    float* wsf = big ? (float*)((char*)d_ws + 2097152) : (float*)d_ws;
    float* u  = mid ? wsf           : out;
    float* v  = mid ? wsf + 8192    : out + 8192;
    float* xx = mid ? wsf + 16384   : out + 40960;
    float* yy = mid ? wsf + 24576   : out + 49152;

    k_init<<<8, 1024, 0, stream>>>(u, v);
    k_sqnorm<<<NN + MMX, 64, 0, stream>>>(XP, XQ, xx, yy);
    k_gemm_mr<<<dim3(64, 64), 256, 0, stream>>>(XP, XQ, xx, yy, Mr);
    if (big) k_xqt<<<256, 256, 0, stream>>>(XQ, XQT32);

    for (int it = 0; it < NITER; ++it) {
        if (mid) k_colpass2<<<dim3(16, 64), 256, 0, stream>>>(Mr, u, part);
        else     k_colpass<<<dim3(8, 64), 256, 0, stream>>>(Mr, u, part);
        k_colcombine<<<32, 256, 0, stream>>>(part, v);
        k_rowpass<<<1024, 256, 0, stream>>>(Mr, v, u);
    }

    if (big) {
        k_pi_mapped_mfma<<<256, 512, 0, stream>>>(Mr, XQT32, u, v, out);
    } else if (mid) {
        k_pi_mapped<<<256, 512, 0, stream>>>(Mr, XQ, u, v, out);
    } else {
        k_pi<<<2048, 256, 0, stream>>>(Mr, u, v);
        k_mapped<<<256, 256, 0, stream>>>(Mr, XQ, out);
    }
}